// Round 1
// baseline (412.413 us; speedup 1.0000x reference)
//
#include <hip/hip_runtime.h>

// BoostedNeuralLDPCDecoder — MI355X HIP implementation
//
// Structure per iteration:
//   cn_kernel: thread = (cn, b, z_c). Reads tot (VN beliefs) + old c2v (int8,
//              value*2), computes extrinsic v2c = clip(tot - c2v), min-sum with
//              exact reference tie semantics (all mins masked for min2),
//              sign parity via XOR, QMS5 quantize, writes new c2v (int8).
//   vn_kernel: block = (b, z-chunk of 64). For each VN n: sum of 0.5*c2v over
//              its edges (exact: half-integers), + ch -> tot (next iter) and
//              out[it] via LDS tile transpose (n-fastest contiguous store).
//
// Layouts (lane = z => coalesced, incl. shifted circulant access):
//   tot  [N][B][Z] float   (6.68 MB)
//   c2v  [E][B][Z] int8    (9.04 MB)  value = 2*message, in [-15,15]
//   vn_deg[N], vn_edges[N][64] built per-launch from edge_vn.

#define ITERS 5
#define Nn 68
#define Mm 46
#define Zz 384
#define Ee 368
#define Bb 64
#define Kk 8          // edges per CN (E/M)
#define MAXD 64
#define BIGF 1e9f

#define TOT_ELEMS (Nn*Bb*Zz)             // 1,671,168 floats
#define C2V_BYTES (Ee*Bb*Zz)             // 9,043,968 bytes
#define TOT_OFF   0
#define C2V_OFF   (TOT_ELEMS*4)          // 6,684,672
#define DEG_OFF   (C2V_OFF + C2V_BYTES)  // 15,728,640
#define EDG_OFF   (DEG_OFF + 384)        // 15,729,024
// total ws need: EDG_OFF + Nn*MAXD*4 = 15,746,432 bytes (~15.8 MB)

__global__ __launch_bounds__(256) void init_kernel(
    const float* __restrict__ xa, const int* __restrict__ edge_vn,
    float* __restrict__ tot, signed char* __restrict__ c2v,
    int* __restrict__ vn_deg, int* __restrict__ vn_edges)
{
    const int R1 = TOT_ELEMS / 4;    // 417,792 float4 (tot init = permuted xa copy)
    int bid = blockIdx.x;
    if (bid < 3840) {                // 3840*256 = 983,040 = R1 + C2V_BYTES/16 exactly
        int idx = bid * 256 + threadIdx.x;
        if (idx < R1) {
            int row = idx / 96;      // 96 float4 per z-row of 384
            int zi  = idx - row * 96;
            int n = row >> 6;        // row = n*B + b, B = 64
            int b = row & 63;
            const float4* src = (const float4*)(xa + (size_t)(b * Nn + n) * Zz);
            ((float4*)tot)[idx] = src[zi];
        } else {
            int j = idx - R1;        // zero c2v, 16 B per thread
            ((int4*)c2v)[j] = make_int4(0, 0, 0, 0);
        }
    } else {
        // build per-VN edge lists (one tiny block; wave-uniform use later)
        int n = threadIdx.x;
        if (n < Nn) {
            int d = 0;
            for (int e = 0; e < Ee; e++) {
                if (edge_vn[e] == n) {
                    if (d < MAXD) vn_edges[n * MAXD + d] = e;
                    d++;
                }
            }
            vn_deg[n] = (d > MAXD) ? MAXD : d;
        }
    }
}

__global__ __launch_bounds__(384) void cn_kernel(
    const float* __restrict__ tot, signed char* __restrict__ c2v,
    const int* __restrict__ edge_vn, const int* __restrict__ edge_shift,
    const float* __restrict__ cn_weight, int it)
{
    const int cn = blockIdx.x;       // [0, M)
    const int b  = blockIdx.y;       // [0, B)
    const int zc = threadIdx.x;      // [0, Z) — CN-domain lifted row
    const float w = cn_weight[it];

    float v[Kk];
    int   off[Kk];
    float m1 = BIGF;
    unsigned sflip = 0u;

    #pragma unroll
    for (int k = 0; k < Kk; k++) {
        int e  = cn + k * Mm;        // edges of this check (edge_cn = e % M)
        int sh = edge_shift[e];      // block-uniform -> scalar load
        int n  = edge_vn[e];         // block-uniform
        int z  = zc - sh;
        z += (z >> 31) & Zz;         // mod Z
        int o = (e * Bb + b) * Zz + z;
        off[k] = o;
        float t = tot[(n * Bb + b) * Zz + z];     // VN belief at VN-domain row z
        float c = 0.5f * (float)c2v[o];           // exact decode
        float x = t - c;                          // extrinsic (one rounding, = ref)
        x = fminf(20.0f, fmaxf(-20.0f, x));       // allowed_llr_range
        v[k] = x;
        if (x < 0.0f) sflip ^= 1u;
        m1 = fminf(m1, fabsf(x));
    }

    // min2 over entries whose |v| != min1 (reference tie semantics, BIG if none)
    float m2 = BIGF;
    #pragma unroll
    for (int k = 0; k < Kk; k++) {
        float mag = fabsf(v[k]);
        if (mag != m1) m2 = fminf(m2, mag);
    }

    #pragma unroll
    for (int k = 0; k < Kk; k++) {
        float mag  = fabsf(v[k]);
        float emin = (mag == m1) ? m2 : m1;
        unsigned neg = sflip ^ ((v[k] < 0.0f) ? 1u : 0u);  // csign * own_sign
        float ext = neg ? -emin : emin;
        // _qms5(w * ext): forward == clip(rintf(2*x)/2, +-7.5); store 2*q as int8
        float r = rintf(w * ext * 2.0f);
        r = fminf(15.0f, fmaxf(-15.0f, r));
        c2v[off[k]] = (signed char)(int)r;
    }
}

__global__ __launch_bounds__(256) void vn_kernel(
    const float* __restrict__ xa, const signed char* __restrict__ c2v,
    float* __restrict__ tot, float* __restrict__ out,
    const int* __restrict__ vn_deg, const int* __restrict__ vn_edges)
{
    __shared__ float tile[64][Nn + 1];   // +1 pad: stride 69 (odd) -> conflict-free
    const int b  = blockIdx.x;
    const int z0 = blockIdx.y * 64;
    const int wave = threadIdx.x >> 6;
    const int lane = threadIdx.x & 63;
    const int z = z0 + lane;

    for (int n = wave; n < Nn; n += 4) {
        int d = vn_deg[n];                       // wave-uniform
        const int* el = vn_edges + n * MAXD;
        float acc = 0.0f;                        // sum of half-integers: exact
        for (int j = 0; j < d; j++) {
            int e = el[j];                       // wave-uniform -> scalar load
            acc += 0.5f * (float)c2v[(e * Bb + b) * Zz + z];
        }
        float s = xa[(size_t)(b * Nn + n) * Zz + z] + acc;  // one rounding, = ref
        tot[(n * Bb + b) * Zz + z] = s;          // belief for next iteration
        tile[lane][n] = s;
    }
    __syncthreads();

    // out[it][b][z][n]: chunk (all n, z in [z0,z0+64)) is 4352 contiguous floats
    float* dst = out + ((size_t)b * Zz + z0) * Nn;
    for (int idx = threadIdx.x; idx < 64 * Nn; idx += 256) {
        int zz = idx / Nn;
        int nn = idx - zz * Nn;
        dst[idx] = tile[zz][nn];
    }
}

extern "C" void kernel_launch(void* const* d_in, const int* in_sizes, int n_in,
                              void* d_out, int out_size, void* d_ws, size_t ws_size,
                              hipStream_t stream) {
    const float* xa        = (const float*)d_in[0];  // [B][N][Z]
    const float* cn_weight = (const float*)d_in[1];  // [ITERS]
    const int*   edge_vn   = (const int*)d_in[2];    // [E]
    // d_in[3] = edge_cn: structurally e % M, not needed
    const int*   edge_shift= (const int*)d_in[4];    // [E]
    float* out = (float*)d_out;                      // [ITERS][B][Z][N]

    char* ws = (char*)d_ws;
    float*       tot      = (float*)(ws + TOT_OFF);
    signed char* c2v      = (signed char*)(ws + C2V_OFF);
    int*         vn_deg   = (int*)(ws + DEG_OFF);
    int*         vn_edges = (int*)(ws + EDG_OFF);

    init_kernel<<<3841, 256, 0, stream>>>(xa, edge_vn, tot, c2v, vn_deg, vn_edges);

    for (int it = 0; it < ITERS; it++) {
        cn_kernel<<<dim3(Mm, Bb), 384, 0, stream>>>(tot, c2v, edge_vn, edge_shift,
                                                    cn_weight, it);
        vn_kernel<<<dim3(Bb, Zz / 64), 256, 0, stream>>>(xa, c2v, tot,
                                                         out + (size_t)it * Bb * Zz * Nn,
                                                         vn_deg, vn_edges);
    }
}

// Round 2
// 194.721 us; speedup vs baseline: 2.1180x; 2.1180x over previous
//
#include <hip/hip_runtime.h>

// BoostedNeuralLDPCDecoder — MI355X HIP implementation (round 2)
//
// Round-2 changes vs round 1 (which was vn-latency-bound: 54.6us/dispatch,
// occupancy 13.7%, VALUBusy 5%):
//  * vn_kernel: N split into 4 chunks of 17 -> 1536 blocks (24 waves/CU);
//    padded per-VN offset table voff[n][24] (dummy slots hit a zeroed extra
//    c2v row) makes the gather fixed-unrolled groups of 8 INDEPENDENT loads
//    (table reads are wave-uniform scalar loads) instead of a dependent
//    e-load -> c2v-load chain per edge. Byte sum accumulated as int (exact).
//  * init_kernel: table build now stages edge_vn in LDS (broadcast reads)
//    instead of 368 serial global loads per thread.
//  * tot store skipped on the last iteration (value unused).
//
// Layouts (lane = z => coalesced, incl. shifted circulant access):
//   tot  [N][B][Z] float      (6.68 MB)
//   c2v  [E+1][B][Z] int8     (9.07 MB) value = 2*message in [-15,15]; row E = zeros
//   vn_deg[N], voff[N][24] (byte offsets e*B*Z; dummy = E*B*Z)

#define ITERS 5
#define Nn 68
#define Mm 46
#define Zz 384
#define Ee 368
#define Bb 64
#define Kk 8          // edges per CN (E/M)
#define PADD 24       // padded max VN degree (P(overflow) ~ 1e-7 for random graph)
#define BIGF 1e9f

#define ROWB (Bb*Zz)                     // 24,576 bytes per c2v edge-row
#define TOT_ELEMS (Nn*Bb*Zz)             // 1,671,168 floats
#define C2V_BYTES ((Ee+1)*ROWB)          // 9,068,544 bytes (incl. zero row)
#define TOT_OFF   0
#define C2V_OFF   (TOT_ELEMS*4)          // 6,684,672
#define DEG_OFF   (C2V_OFF + C2V_BYTES)  // 15,753,216
#define VOFF_OFF  (DEG_OFF + 384)        // 15,753,600
// total ws need: VOFF_OFF + Nn*PADD*4 = 15,760,128 bytes (~15.8 MB)

#define R1 (TOT_ELEMS/4)                 // 417,792 float4 copies
#define RC (C2V_BYTES/16)                // 566,784 int4 zeroes
#define NCOPY ((R1+RC)/256)              // 3846 (exact)

__global__ __launch_bounds__(256) void init_kernel(
    const float* __restrict__ xa, const int* __restrict__ edge_vn,
    float* __restrict__ tot, signed char* __restrict__ c2v,
    int* __restrict__ vn_deg, int* __restrict__ voff)
{
    int bid = blockIdx.x;
    if (bid < NCOPY) {
        int idx = bid * 256 + threadIdx.x;
        if (idx < R1) {
            // tot init = xa permuted [B][N][Z] -> [N][B][Z]
            int row = idx / 96;      // 96 float4 per z-row of 384
            int zi  = idx - row * 96;
            int n = row >> 6;        // row = n*B + b
            int b = row & 63;
            const float4* src = (const float4*)(xa + (size_t)(b * Nn + n) * Zz);
            ((float4*)tot)[idx] = src[zi];
        } else {
            int j = idx - R1;        // zero all E+1 c2v rows, 16 B per thread
            ((int4*)c2v)[j] = make_int4(0, 0, 0, 0);
        }
    } else {
        // build padded per-VN offset table; LDS staging kills the load chain
        __shared__ int sev[Ee];
        for (int t = threadIdx.x; t < Ee; t += 256) sev[t] = edge_vn[t];
        __syncthreads();
        int n = threadIdx.x;
        if (n < Nn) {
            int d = 0;
            for (int e = 0; e < Ee; e++)
                if (sev[e] == n && d < PADD) voff[n * PADD + (d++)] = e * ROWB;
            vn_deg[n] = d;
            for (int j = d; j < PADD; j++) voff[n * PADD + j] = Ee * ROWB; // zero row
        }
    }
}

__global__ __launch_bounds__(384) void cn_kernel(
    const float* __restrict__ tot, signed char* __restrict__ c2v,
    const int* __restrict__ edge_vn, const int* __restrict__ edge_shift,
    const float* __restrict__ cn_weight, int it)
{
    const int cn = blockIdx.x;       // [0, M)
    const int b  = blockIdx.y;       // [0, B)
    const int zc = threadIdx.x;      // [0, Z) — CN-domain lifted row
    const float w = cn_weight[it];

    float v[Kk];
    int   off[Kk];
    float m1 = BIGF;
    unsigned sflip = 0u;

    #pragma unroll
    for (int k = 0; k < Kk; k++) {
        int e  = cn + k * Mm;        // edges of this check (edge_cn = e % M)
        int sh = edge_shift[e];      // block-uniform -> scalar load
        int n  = edge_vn[e];         // block-uniform
        int z  = zc - sh;
        z += (z >> 31) & Zz;         // mod Z
        int o = e * ROWB + b * Zz + z;
        off[k] = o;
        float t = tot[(n * Bb + b) * Zz + z];     // VN belief at VN-domain row z
        float c = 0.5f * (float)c2v[o];           // exact decode
        float x = t - c;                          // extrinsic (one rounding, = ref)
        x = fminf(20.0f, fmaxf(-20.0f, x));       // allowed_llr_range
        v[k] = x;
        if (x < 0.0f) sflip ^= 1u;
        m1 = fminf(m1, fabsf(x));
    }

    // min2 over entries whose |v| != min1 (reference tie semantics, BIG if none)
    float m2 = BIGF;
    #pragma unroll
    for (int k = 0; k < Kk; k++) {
        float mag = fabsf(v[k]);
        if (mag != m1) m2 = fminf(m2, mag);
    }

    #pragma unroll
    for (int k = 0; k < Kk; k++) {
        float mag  = fabsf(v[k]);
        float emin = (mag == m1) ? m2 : m1;
        unsigned neg = sflip ^ ((v[k] < 0.0f) ? 1u : 0u);  // csign * own_sign
        float ext = neg ? -emin : emin;
        // _qms5(w * ext): forward == clip(rintf(2*x)/2, +-7.5); store 2*q as int8
        float r = rintf(w * ext * 2.0f);
        r = fminf(15.0f, fmaxf(-15.0f, r));
        c2v[off[k]] = (signed char)(int)r;
    }
}

__global__ __launch_bounds__(256) void vn_kernel(
    const float* __restrict__ xa, const signed char* __restrict__ c2v,
    float* __restrict__ tot, float* __restrict__ out,
    const int* __restrict__ vn_deg, const int* __restrict__ voff,
    int write_tot)
{
    __shared__ float tile[17][65];   // [n_local][z_local+1 pad]
    const int b  = blockIdx.x;
    const int z0 = blockIdx.y * 64;
    const int n0 = blockIdx.z * 17;
    const int wave = threadIdx.x >> 6;
    const int lane = threadIdx.x & 63;
    const int z = z0 + lane;
    const int bz = b * Zz + z;       // offset within a c2v edge-row

    for (int i = wave; i < 17; i += 4) {
        int n = __builtin_amdgcn_readfirstlane(n0 + i);  // force scalar table loads
        int d = vn_deg[n];                               // wave-uniform
        const int* vo = voff + n * PADD;
        int acc = 0;                 // sum of int8 messages (2x value): exact
        #pragma unroll
        for (int j = 0; j < 8; j++) acc += (int)c2v[vo[j] + bz];   // 8 indep loads
        if (d > 8) {
            #pragma unroll
            for (int j = 8; j < 16; j++) acc += (int)c2v[vo[j] + bz];
        }
        if (d > 16) {
            #pragma unroll
            for (int j = 16; j < PADD; j++) acc += (int)c2v[vo[j] + bz];
        }
        float s = xa[(size_t)(b * Nn + n) * Zz + z] + 0.5f * (float)acc; // one rounding
        if (write_tot) tot[(n * Bb + b) * Zz + z] = s;   // belief for next iteration
        tile[i][lane] = s;
    }
    __syncthreads();

    // out[it][b][z][n]: this block covers z in [z0,z0+64) x n in [n0,n0+17)
    // -> 64 contiguous 68B segments; L2 merges the 4 n-chunk blocks' segments.
    float* dst = out + ((size_t)b * Zz + z0) * Nn + n0;
    for (int idx = threadIdx.x; idx < 17 * 64; idx += 256) {
        int zz = idx / 17;
        int nn = idx - zz * 17;
        dst[(size_t)zz * Nn + nn] = tile[nn][zz];
    }
}

extern "C" void kernel_launch(void* const* d_in, const int* in_sizes, int n_in,
                              void* d_out, int out_size, void* d_ws, size_t ws_size,
                              hipStream_t stream) {
    const float* xa        = (const float*)d_in[0];  // [B][N][Z]
    const float* cn_weight = (const float*)d_in[1];  // [ITERS]
    const int*   edge_vn   = (const int*)d_in[2];    // [E]
    // d_in[3] = edge_cn: structurally e % M, not needed
    const int*   edge_shift= (const int*)d_in[4];    // [E]
    float* out = (float*)d_out;                      // [ITERS][B][Z][N]

    char* ws = (char*)d_ws;
    float*       tot    = (float*)(ws + TOT_OFF);
    signed char* c2v    = (signed char*)(ws + C2V_OFF);
    int*         vn_deg = (int*)(ws + DEG_OFF);
    int*         voff   = (int*)(ws + VOFF_OFF);

    init_kernel<<<NCOPY + 1, 256, 0, stream>>>(xa, edge_vn, tot, c2v, vn_deg, voff);

    for (int it = 0; it < ITERS; it++) {
        cn_kernel<<<dim3(Mm, Bb), 384, 0, stream>>>(tot, c2v, edge_vn, edge_shift,
                                                    cn_weight, it);
        vn_kernel<<<dim3(Bb, Zz / 64, 4), 256, 0, stream>>>(
            xa, c2v, tot, out + (size_t)it * Bb * Zz * Nn,
            vn_deg, voff, (it != ITERS - 1) ? 1 : 0);
    }
}